// Round 11
// baseline (3958.869 us; speedup 1.0000x reference)
//
#include <hip/hip_runtime.h>
#include <cstdint>
#include <cstddef>

// Problem constants (fixed by reference setup_inputs)
constexpr int Bb = 8;
constexpr int Nn = 8192;
constexpr int Ss = 2048;
constexpr int BS = Bb * Ss;  // 16384

typedef float vfloat2 __attribute__((ext_vector_type(2)));

// ---------------------------------------------------------------------------
// FPS: one block per batch, 1024 threads, 8 points/thread (proven shape).
// dist[] updates exact f64 (bit-matches np, verified r1-r10); certified f32
// screening skips only provable non-updates. Exact atomic reduce (r10).
// Round-11: wave f32-max shuffle chain runs ONLY when a lane that was at the
// wave top changed (values only decrease -> if no top lane updated, the wave
// max and its f32 image are provably unchanged). Decisions bit-identical.
// ---------------------------------------------------------------------------
__global__ __launch_bounds__(1024) void fps_kernel(const float* __restrict__ xyz,
                                                   float* __restrict__ new_xyz) {
  __shared__ float lx[Nn * 3];             // 96 KB: batch point cloud
  __shared__ int sidx[Ss];                 // 8 KB: selected-index log
  __shared__ unsigned long long slotV[2];  // parity: f64-bit global max
  __shared__ int slotI[2];                 // parity: winner index (min over ties)
  const int b = blockIdx.x;
  const int tid = threadIdx.x;
  const float* xb = xyz + (size_t)b * Nn * 3;
  for (int e = tid; e < Nn * 3; e += 1024) lx[e] = xb[e];
  if (tid == 0) {
    slotV[0] = 0ull; slotV[1] = 0ull;
    slotI[0] = 0x7fffffff; slotI[1] = 0x7fffffff;
  }
  __syncthreads();

  vfloat2 px2[4], py2[4], pz2[4], df2[4];
  double dist[8];
#pragma unroll
  for (int jj = 0; jj < 4; ++jj) {
    const int p0 = tid + (2 * jj) * 1024, p1 = tid + (2 * jj + 1) * 1024;
    px2[jj] = (vfloat2){lx[p0 * 3 + 0], lx[p1 * 3 + 0]};
    py2[jj] = (vfloat2){lx[p0 * 3 + 1], lx[p1 * 3 + 1]};
    pz2[jj] = (vfloat2){lx[p0 * 3 + 2], lx[p1 * 3 + 2]};
    df2[jj] = (vfloat2){3.0e38f, 3.0e38f};   // force exact path on first touch
    dist[2 * jj] = 1e10;
    dist[2 * jj + 1] = 1e10;
  }
  float lmax = 3.0e38f;                    // cached max of certified bounds
  int cur = 0;
  double lv = -1.0;                        // per-lane cached local max (exact)
  int li = 0x7fffffff;
  float lv32 = -1.0f;                      // cached (float)lv
  float wv32_c = -1.0f;                    // cached wave f32 max
  for (int i = 0; i < Ss; ++i) {
    if (tid == 0) sidx[i] = cur;           // LDS log (visible after barrier)
    const float cxf = lx[cur * 3 + 0], cyf = lx[cur * 3 + 1], czf = lx[cur * 3 + 2];
    const vfloat2 cx2 = {cxf, cxf}, cy2 = {cyf, cyf}, cz2 = {czf, czf};
    const bool wasTop = (lv32 == wv32_c);  // latched BEFORE updates
    // ---- packed-f32 distances ----
    vfloat2 d2v[4];
#pragma unroll
    for (int jj = 0; jj < 4; ++jj) {
      const vfloat2 dx = px2[jj] - cx2;
      const vfloat2 dy = py2[jj] - cy2;
      const vfloat2 dz = pz2[jj] - cz2;
      d2v[jj] = dx * dx + dy * dy + dz * dz;
    }
    const float dmin = fminf(fminf(fminf(d2v[0].x, d2v[0].y), fminf(d2v[1].x, d2v[1].y)),
                             fminf(fminf(d2v[2].x, d2v[2].y), fminf(d2v[3].x, d2v[3].y)));
    bool changed = false;
    if (dmin <= lmax) {                    // necessary condition for any update
#pragma unroll
      for (int j = 0; j < 8; ++j) {
        const float d2s = d2v[j >> 1][j & 1];
        const float dfs = (j & 1) ? df2[j >> 1].y : df2[j >> 1].x;
        if (d2s <= dfs) {                  // certified screen -> exact f64
          const float pxs = px2[j >> 1][j & 1];
          const float pys = py2[j >> 1][j & 1];
          const float pzs = pz2[j >> 1][j & 1];
          double dx = __dsub_rn((double)pxs, (double)cxf);
          double dy = __dsub_rn((double)pys, (double)cyf);
          double dz = __dsub_rn((double)pzs, (double)czf);
          double d = __dadd_rn(__dadd_rn(__dmul_rn(dx, dx), __dmul_rn(dy, dy)),
                               __dmul_rn(dz, dz));
          if (d < dist[j]) {
            dist[j] = d;
            const float dfn = (float)d * 1.000002f;  // certified upper bound
            if (j & 1) df2[j >> 1].y = dfn; else df2[j >> 1].x = dfn;
            changed = true;
          }
        }
      }
      if (changed) {                       // rescan local max + refresh lmax
        lv = -1.0;
        li = 0;
#pragma unroll
        for (int j = 0; j < 8; ++j) {
          if (dist[j] > lv) { lv = dist[j]; li = tid + j * 1024; }  // j asc => min idx on tie
        }
        lv32 = (float)lv;
        lmax = fmaxf(fmaxf(fmaxf(df2[0].x, df2[0].y), fmaxf(df2[1].x, df2[1].y)),
                     fmaxf(fmaxf(df2[2].x, df2[2].y), fmaxf(df2[3].x, df2[3].y)));
      }
    }
    // wave f32 max needs recompute only if a former top lane changed
    const unsigned long long topChanged = __ballot(changed && wasTop);
    if (topChanged) {
      float m32 = lv32;
#pragma unroll
      for (int off = 1; off < 64; off <<= 1) m32 = fmaxf(m32, __shfl_xor(m32, off));
      wv32_c = m32;
    }
    const int pb = i & 1;
    // candidate lanes (contain the exact f64 wave max by monotonicity)
    if (lv32 == wv32_c) atomicMax(&slotV[pb], (unsigned long long)__double_as_longlong(lv));
    __syncthreads();
    const double W = __longlong_as_double((long long)slotV[pb]);
    if (lv == W) atomicMin(&slotI[pb], li);
    if (tid == 0) {                        // reset other parity for iter i+1
      slotV[pb ^ 1] = 0ull;
      slotI[pb ^ 1] = 0x7fffffff;
    }
    __syncthreads();
    cur = slotI[pb];
  }
  __syncthreads();
  // final gather: new_xyz[i][c] = lx[sidx[i]*3 + c]
  float* nxb = new_xyz + (size_t)b * Ss * 3;
  for (int e = tid; e < Ss * 3; e += 1024) {
    const int i = e / 3, c = e - i * 3;
    nxb[e] = lx[sidx[i] * 3 + c];
  }
}

// ---------------------------------------------------------------------------
// Ball query, both scales fused. One wave per center. f64 distance compare
// (bit-matches np). First nsample in-range points in original order; pad with
// first hit (0 if none).
// ---------------------------------------------------------------------------
__global__ __launch_bounds__(256) void ballq_kernel(const float* __restrict__ xyz,
                                                    const float* __restrict__ nxyz,
                                                    int* __restrict__ idx0,
                                                    int* __restrict__ idx1) {
  const int wid = threadIdx.x >> 6, lane = threadIdx.x & 63;
  const int bs = blockIdx.x * 4 + wid;
  const int b = bs >> 11;  // S = 2048
  const float* xb = xyz + (size_t)b * Nn * 3;
  const double cx = (double)nxyz[bs * 3 + 0];
  const double cy = (double)nxyz[bs * 3 + 1];
  const double cz = (double)nxyz[bs * 3 + 2];
  const double R0 = 0.4 * 0.4, R1 = 0.8 * 0.8;
  int cnt0 = 0, cnt1 = 0, first0 = 0, first1 = 0;
  const unsigned long long lmask = (1ull << lane) - 1ull;
  for (int base = 0; base < Nn; base += 64) {
    const int p = base + lane;
    double dx = __dsub_rn((double)xb[p * 3 + 0], cx);
    double dy = __dsub_rn((double)xb[p * 3 + 1], cy);
    double dz = __dsub_rn((double)xb[p * 3 + 2], cz);
    double d2 = __dadd_rn(__dadd_rn(__dmul_rn(dx, dx), __dmul_rn(dy, dy)), __dmul_rn(dz, dz));
    const bool in0 = d2 < R0, in1 = d2 < R1;
    unsigned long long m0 = __ballot(in0);
    unsigned long long m1 = __ballot(in1);
    if (cnt0 < 16 && m0) {
      if (cnt0 == 0) first0 = base + __builtin_ctzll(m0);
      int r = (int)__popcll(m0 & lmask);
      if (in0 && cnt0 + r < 16) idx0[bs * 16 + cnt0 + r] = p;
      cnt0 += (int)__popcll(m0);
    }
    if (cnt1 < 32 && m1) {
      if (cnt1 == 0) first1 = base + __builtin_ctzll(m1);
      int r = (int)__popcll(m1 & lmask);
      if (in1 && cnt1 + r < 32) idx1[bs * 32 + cnt1 + r] = p;
      cnt1 += (int)__popcll(m1);
    }
    if (cnt0 >= 16 && cnt1 >= 32) break;
  }
  const int f0 = cnt0 < 16 ? cnt0 : 16;
  for (int j = f0 + lane; j < 16; j += 64) idx0[bs * 16 + j] = first0;
  const int f1 = cnt1 < 32 ? cnt1 : 32;
  for (int j = f1 + lane; j < 32; j += 64) idx1[bs * 32 + j] = first1;
}

// ---------------------------------------------------------------------------
// Generic tall-skinny GEMM with fused input transforms and BN-stat atomics.
// Tile: 64 rows x COUT cols, 256 threads, per-thread 4 rows x (COUT/16) cols.
// MODE 0: gather (rel-xyz ++ features) via ball-query idx          (K=67)
// MODE 1: x = relu(bn(prev_raw)) from 64-ch buffer (in-place safe) (K=64)
// MODE 2: x = concat(relu(bn(pool0)), relu(bn(pool1)))             (K=256)
// MODE 4: x = relu(bn(xin)) from 256-ch buffer; also writes x to hw (K=256)
// BN stats arrive as raw global [sum(C), sumsq(C)] (stIn/stIn2 + invM);
// mu/rstd computed inline into LDS. Epilogue atomicAdds this layer's
// per-channel (sum, sumsq) into Sout (f32, order-random — BN tolerance ok).
// POOL: write per-group (NS) max of raw output instead of full rows.
// ---------------------------------------------------------------------------
template <int COUT, int KTOT, int MODE, int NS, bool POOL, bool BIAS>
__global__ __launch_bounds__(256) void mlp_gemm(
    const float* __restrict__ xin, const float* __restrict__ xin2,
    const float* __restrict__ stIn, const float* __restrict__ stIn2,
    float invM1, float invM2,
    const float* __restrict__ w, const float* __restrict__ bias,
    const int* __restrict__ gidx, const float* __restrict__ xyz,
    const float* __restrict__ nxyz, const float* __restrict__ feats,
    float* __restrict__ hw, float* __restrict__ out, float* __restrict__ Sout) {
  constexpr int KC = (KTOT <= 68) ? KTOT : 32;     // K chunk
  constexpr int NCH = (KTOT + KC - 1) / KC;
  constexpr int TC = COUT / 16;                    // cols per thread
  constexpr int XPAD = KC + 1;
  constexpr int XSZ = 64 * XPAD;
  constexpr int EPI = (POOL ? 48 : 32) * COUT;
  constexpr int SM = (XSZ + KC * COUT > EPI) ? (XSZ + KC * COUT) : EPI;
  constexpr int BNSZ = (MODE == 0) ? 0 : 512;
  __shared__ float smem[SM + BNSZ];
  float* xS = smem;
  float* wS = smem + XSZ;
  float* bnM = smem + SM;                  // persists (outside reused region)
  float* bnR = smem + SM + 256;

  const int tid = threadIdx.x;
  const int cg = tid & 15, rg = tid >> 4;
  const int row0 = blockIdx.x * 64;

  if constexpr (MODE != 0) {               // inline BN finalize -> LDS
    for (int c = tid; c < KTOT; c += 256) {
      float sum, sq, im;
      if constexpr (MODE == 2) {
        if (c < 128) { sum = stIn[c]; sq = stIn[128 + c]; im = invM1; }
        else { sum = stIn2[c - 128]; sq = stIn2[c]; im = invM2; }
      } else {
        constexpr int C = (MODE == 1) ? 64 : 256;
        sum = stIn[c]; sq = stIn[C + c]; im = invM1;
      }
      const float mu = sum * im;
      const float var = sq * im - mu * mu;
      bnM[c] = mu;
      bnR[c] = 1.0f / sqrtf(var + 1e-5f);
    }
    __syncthreads();
  }

  float acc[4][TC];
#pragma unroll
  for (int i = 0; i < 4; ++i)
#pragma unroll
    for (int t = 0; t < TC; ++t) acc[i][t] = 0.f;

  for (int ch = 0; ch < NCH; ++ch) {
    const int k0 = ch * KC;
    if (ch) __syncthreads();
    // ---- stage x tile [64 rows][KC] (row-major, padded) ----
    for (int e = tid; e < 64 * KC; e += 256) {
      const int r = e / KC, kk = e - r * KC;
      const int kg = k0 + kk;
      const int rowg = row0 + r;
      float v;
      if constexpr (MODE == 0) {
        const int bs = rowg / NS;
        const int p = gidx[rowg];
        const int bb = bs >> 11;
        if (kg < 3)
          v = xyz[(bb * Nn + p) * 3 + kg] - nxyz[bs * 3 + kg];
        else
          v = feats[((bb * Nn + p) << 6) + (kg - 3)];
      } else if constexpr (MODE == 1) {
        v = fmaxf((xin[(size_t)rowg * 64 + kg] - bnM[kg]) * bnR[kg], 0.f);
      } else if constexpr (MODE == 2) {
        if (kg < 128)
          v = fmaxf((xin[(size_t)rowg * 128 + kg] - bnM[kg]) * bnR[kg], 0.f);
        else
          v = fmaxf((xin2[(size_t)rowg * 128 + (kg - 128)] - bnM[kg]) * bnR[kg], 0.f);
      } else {  // MODE 4
        v = fmaxf((xin[(size_t)rowg * 256 + kg] - bnM[kg]) * bnR[kg], 0.f);
        hw[(size_t)rowg * 256 + kg] = v;
      }
      xS[r * XPAD + kk] = v;
    }
    // ---- stage w chunk [KC][COUT] ----
    for (int e = tid; e < KC * COUT; e += 256) {
      const int kk = e / COUT, c = e - kk * COUT;
      wS[kk * COUT + c] = w[(size_t)(k0 + kk) * COUT + c];
    }
    __syncthreads();
    // ---- FMA loop ----
    for (int kk = 0; kk < KC; ++kk) {
      float xr[4];
#pragma unroll
      for (int i = 0; i < 4; ++i) xr[i] = xS[(rg * 4 + i) * XPAD + kk];
#pragma unroll
      for (int t = 0; t < TC; t += 4) {
        const float4 wv = *(const float4*)&wS[kk * COUT + cg * TC + t];
#pragma unroll
        for (int i = 0; i < 4; ++i) {
          acc[i][t + 0] = fmaf(xr[i], wv.x, acc[i][t + 0]);
          acc[i][t + 1] = fmaf(xr[i], wv.y, acc[i][t + 1]);
          acc[i][t + 2] = fmaf(xr[i], wv.z, acc[i][t + 2]);
          acc[i][t + 3] = fmaf(xr[i], wv.w, acc[i][t + 3]);
        }
      }
    }
  }
  __syncthreads();  // smem reuse below
  if constexpr (BIAS) {
#pragma unroll
    for (int t = 0; t < TC; ++t) {
      const float bv = bias[cg * TC + t];
#pragma unroll
      for (int i = 0; i < 4; ++i) acc[i][t] += bv;
    }
  }
  // ---- per-block BN partials (+ group max for POOL) ----
  float* ssum = smem;
  float* ssq = smem + 16 * COUT;
  float* pbuf = smem + 32 * COUT;
  const int colb = cg * TC;
#pragma unroll
  for (int t = 0; t < TC; ++t) {
    float s = 0.f, q = 0.f, m = -3.4e38f;
#pragma unroll
    for (int i = 0; i < 4; ++i) {
      const float v = acc[i][t];
      s += v;
      q = fmaf(v, v, q);
      m = fmaxf(m, v);
    }
    ssum[rg * COUT + colb + t] = s;
    ssq[rg * COUT + colb + t] = q;
    if constexpr (POOL) pbuf[rg * COUT + colb + t] = m;
  }
  __syncthreads();
  for (int c = tid; c < COUT; c += 256) {
    float s = 0.f, q = 0.f;
#pragma unroll
    for (int rr = 0; rr < 16; ++rr) {
      s += ssum[rr * COUT + c];
      q += ssq[rr * COUT + c];
    }
    atomicAdd(&Sout[c], s);
    atomicAdd(&Sout[COUT + c], q);
  }
  if constexpr (POOL) {
    constexpr int G = 64 / NS, RPG = NS / 4;
    for (int o = tid; o < G * COUT; o += 256) {
      const int g = o / COUT, c = o - g * COUT;
      float m = pbuf[(g * RPG) * COUT + c];
#pragma unroll
      for (int qq = 1; qq < RPG; ++qq) m = fmaxf(m, pbuf[(g * RPG + qq) * COUT + c]);
      out[(size_t)(blockIdx.x * G + g) * COUT + c] = m;
    }
  } else {
#pragma unroll
    for (int i = 0; i < 4; ++i) {
      float* op = out + (size_t)(row0 + rg * 4 + i) * COUT + colb;
#pragma unroll
      for (int t = 0; t < TC; t += 4) {
        *(float4*)(op + t) = make_float4(acc[i][t], acc[i][t + 1], acc[i][t + 2], acc[i][t + 3]);
      }
    }
  }
}

// cls = relu(bn(conf_raw)) @ cls_w + cls_b   (one wave per row; inline BN)
__global__ __launch_bounds__(256) void cls_kernel(const float* __restrict__ craw,
                                                  const float* __restrict__ st,
                                                  const float* __restrict__ clsw,
                                                  const float* __restrict__ clsb,
                                                  float* __restrict__ outc) {
  __shared__ float bnM[256], bnR[256];
  const int tid = threadIdx.x;
  {
    const float im = 1.0f / 16384.0f;
    const float sum = st[tid], sq = st[256 + tid];
    const float mu = sum * im;
    const float var = sq * im - mu * mu;
    bnM[tid] = mu;
    bnR[tid] = 1.0f / sqrtf(var + 1e-5f);
  }
  __syncthreads();
  const int wid = tid >> 6, lane = tid & 63;
  const int row = blockIdx.x * 4 + wid;
  const float* cr = craw + (size_t)row * 256;
  float a0 = 0.f, a1 = 0.f, a2 = 0.f;
#pragma unroll 4
  for (int k = lane; k < 256; k += 64) {
    float x = fmaxf((cr[k] - bnM[k]) * bnR[k], 0.f);
    a0 = fmaf(x, clsw[k * 3 + 0], a0);
    a1 = fmaf(x, clsw[k * 3 + 1], a1);
    a2 = fmaf(x, clsw[k * 3 + 2], a2);
  }
#pragma unroll
  for (int off = 32; off; off >>= 1) {
    a0 += __shfl_down(a0, off);
    a1 += __shfl_down(a1, off);
    a2 += __shfl_down(a2, off);
  }
  if (lane == 0) {
    outc[row * 3 + 0] = a0 + clsb[0];
    outc[row * 3 + 1] = a1 + clsb[1];
    outc[row * 3 + 2] = a2 + clsb[2];
  }
}

// ---------------------------------------------------------------------------
extern "C" void kernel_launch(void* const* d_in, const int* in_sizes, int n_in,
                              void* d_out, int out_size, void* d_ws, size_t ws_size,
                              hipStream_t stream) {
  (void)in_sizes; (void)n_in; (void)out_size; (void)ws_size;
  const float* xyz = (const float*)d_in[0];
  const float* feats = (const float*)d_in[1];
  const float* w00 = (const float*)d_in[2];
  const float* w01 = (const float*)d_in[3];
  const float* w02 = (const float*)d_in[4];
  const float* w10 = (const float*)d_in[5];
  const float* w11 = (const float*)d_in[6];
  const float* w12 = (const float*)d_in[7];
  const float* aggw = (const float*)d_in[8];
  const float* aggb = (const float*)d_in[9];
  const float* confw = (const float*)d_in[10];
  const float* clsw = (const float*)d_in[11];
  const float* clsb = (const float*)d_in[12];

  float* outp = (float*)d_out;
  float* nxyz = outp;                               // [BS,3]
  float* hout = outp + (size_t)BS * 3;              // [BS,256]
  float* clsout = hout + (size_t)BS * 256;          // [BS,3]

  char* ws = (char*)d_ws;
  const size_t MB = 1u << 20;
  int* idx0 = (int*)(ws + 0);                       // 1 MB
  int* idx1 = (int*)(ws + 1 * MB);                  // 2 MB
  float* st = (float*)(ws + 3 * MB);                // BN stats: 2048 floats
  float* pool0 = (float*)(ws + 12 * MB);            // [BS,128]
  float* pool1 = (float*)(ws + 20 * MB);            // [BS,128]
  float* aggraw = (float*)(ws + 28 * MB);           // [BS,256]
  float* confraw = (float*)(ws + 44 * MB);          // [BS,256]
  float* hA = (float*)(ws + 60 * MB);               // [524288,64] (layers 1/2 in-place)

  // stats offsets (floats): s0L1=0 s0L2=128 s0L3=256 s1L1=512 s1L2=640
  //                         s1L3=768 agg=1024 conf=1536
  hipMemsetAsync(st, 0, 2048 * sizeof(float), stream);

  const float iM0 = 1.0f / 262144.0f;   // scale0 rows
  const float iM1 = 1.0f / 524288.0f;   // scale1 rows
  const float iMh = 1.0f / 16384.0f;    // BS rows

  fps_kernel<<<Bb, 1024, 0, stream>>>(xyz, nxyz);
  ballq_kernel<<<BS / 4, 256, 0, stream>>>(xyz, nxyz, idx0, idx1);

  // ---- scale 0 (r=0.4, ns=16) ----
  mlp_gemm<64, 67, 0, 16, false, false><<<4096, 256, 0, stream>>>(
      nullptr, nullptr, nullptr, nullptr, 0.f, 0.f, w00, nullptr,
      idx0, xyz, nxyz, feats, nullptr, hA, st + 0);
  mlp_gemm<64, 64, 1, 1, false, false><<<4096, 256, 0, stream>>>(
      hA, nullptr, st + 0, nullptr, iM0, 0.f, w01, nullptr,
      nullptr, nullptr, nullptr, nullptr, nullptr, hA, st + 128);
  mlp_gemm<128, 64, 1, 16, true, false><<<4096, 256, 0, stream>>>(
      hA, nullptr, st + 128, nullptr, iM0, 0.f, w02, nullptr,
      nullptr, nullptr, nullptr, nullptr, nullptr, pool0, st + 256);

  // ---- scale 1 (r=0.8, ns=32) ----
  mlp_gemm<64, 67, 0, 32, false, false><<<8192, 256, 0, stream>>>(
      nullptr, nullptr, nullptr, nullptr, 0.f, 0.f, w10, nullptr,
      idx1, xyz, nxyz, feats, nullptr, hA, st + 512);
  mlp_gemm<64, 64, 1, 1, false, false><<<8192, 256, 0, stream>>>(
      hA, nullptr, st + 512, nullptr, iM1, 0.f, w11, nullptr,
      nullptr, nullptr, nullptr, nullptr, nullptr, hA, st + 640);
  mlp_gemm<128, 64, 1, 32, true, false><<<8192, 256, 0, stream>>>(
      hA, nullptr, st + 640, nullptr, iM1, 0.f, w12, nullptr,
      nullptr, nullptr, nullptr, nullptr, nullptr, pool1, st + 768);

  // ---- aggregation: concat(bn3_0(pool0), bn3_1(pool1)) @ agg_w + agg_b ----
  mlp_gemm<256, 256, 2, 1, false, true><<<256, 256, 0, stream>>>(
      pool0, pool1, st + 256, st + 768, iM0, iM1, aggw, aggb,
      nullptr, nullptr, nullptr, nullptr, nullptr, aggraw, st + 1024);

  // ---- confidence hidden layer (MODE 4: bn+relu(aggraw) -> h to d_out,
  //      GEMM against conf_w) ----
  mlp_gemm<256, 256, 4, 1, false, false><<<256, 256, 0, stream>>>(
      aggraw, nullptr, st + 1024, nullptr, iMh, 0.f, confw, nullptr,
      nullptr, nullptr, nullptr, nullptr, hout, confraw, st + 1536);

  // ---- classifier ----
  cls_kernel<<<BS / 4, 256, 0, stream>>>(confraw, st + 1536, clsw, clsb, clsout);
}

// Round 12
// 3702.436 us; speedup vs baseline: 1.0693x; 1.0693x over previous
//
#include <hip/hip_runtime.h>
#include <cstdint>
#include <cstddef>

// Problem constants (fixed by reference setup_inputs)
constexpr int Bb = 8;
constexpr int Nn = 8192;
constexpr int Ss = 2048;
constexpr int BS = Bb * Ss;  // 16384
constexpr int NSL = 32;      // BN-stat atomic stripe count

typedef float vfloat2 __attribute__((ext_vector_type(2)));

// ---------------------------------------------------------------------------
// FPS: one block per batch, 1024 threads, 8 points/thread (proven shape).
// dist[] updates exact f64 (bit-matches np, verified r1-r11); certified f32
// screening skips only provable non-updates. Exact atomic reduce (r10) +
// wasTop-gated wave max refresh (r11). Unchanged from r11 (2502 us).
// ---------------------------------------------------------------------------
__global__ __launch_bounds__(1024) void fps_kernel(const float* __restrict__ xyz,
                                                   float* __restrict__ new_xyz) {
  __shared__ float lx[Nn * 3];             // 96 KB: batch point cloud
  __shared__ int sidx[Ss];                 // 8 KB: selected-index log
  __shared__ unsigned long long slotV[2];  // parity: f64-bit global max
  __shared__ int slotI[2];                 // parity: winner index (min over ties)
  const int b = blockIdx.x;
  const int tid = threadIdx.x;
  const float* xb = xyz + (size_t)b * Nn * 3;
  for (int e = tid; e < Nn * 3; e += 1024) lx[e] = xb[e];
  if (tid == 0) {
    slotV[0] = 0ull; slotV[1] = 0ull;
    slotI[0] = 0x7fffffff; slotI[1] = 0x7fffffff;
  }
  __syncthreads();

  vfloat2 px2[4], py2[4], pz2[4], df2[4];
  double dist[8];
#pragma unroll
  for (int jj = 0; jj < 4; ++jj) {
    const int p0 = tid + (2 * jj) * 1024, p1 = tid + (2 * jj + 1) * 1024;
    px2[jj] = (vfloat2){lx[p0 * 3 + 0], lx[p1 * 3 + 0]};
    py2[jj] = (vfloat2){lx[p0 * 3 + 1], lx[p1 * 3 + 1]};
    pz2[jj] = (vfloat2){lx[p0 * 3 + 2], lx[p1 * 3 + 2]};
    df2[jj] = (vfloat2){3.0e38f, 3.0e38f};   // force exact path on first touch
    dist[2 * jj] = 1e10;
    dist[2 * jj + 1] = 1e10;
  }
  float lmax = 3.0e38f;                    // cached max of certified bounds
  int cur = 0;
  double lv = -1.0;                        // per-lane cached local max (exact)
  int li = 0x7fffffff;
  float lv32 = -1.0f;                      // cached (float)lv
  float wv32_c = -1.0f;                    // cached wave f32 max
  for (int i = 0; i < Ss; ++i) {
    if (tid == 0) sidx[i] = cur;           // LDS log (visible after barrier)
    const float cxf = lx[cur * 3 + 0], cyf = lx[cur * 3 + 1], czf = lx[cur * 3 + 2];
    const vfloat2 cx2 = {cxf, cxf}, cy2 = {cyf, cyf}, cz2 = {czf, czf};
    const bool wasTop = (lv32 == wv32_c);  // latched BEFORE updates
    // ---- packed-f32 distances ----
    vfloat2 d2v[4];
#pragma unroll
    for (int jj = 0; jj < 4; ++jj) {
      const vfloat2 dx = px2[jj] - cx2;
      const vfloat2 dy = py2[jj] - cy2;
      const vfloat2 dz = pz2[jj] - cz2;
      d2v[jj] = dx * dx + dy * dy + dz * dz;
    }
    const float dmin = fminf(fminf(fminf(d2v[0].x, d2v[0].y), fminf(d2v[1].x, d2v[1].y)),
                             fminf(fminf(d2v[2].x, d2v[2].y), fminf(d2v[3].x, d2v[3].y)));
    bool changed = false;
    if (dmin <= lmax) {                    // necessary condition for any update
#pragma unroll
      for (int j = 0; j < 8; ++j) {
        const float d2s = d2v[j >> 1][j & 1];
        const float dfs = (j & 1) ? df2[j >> 1].y : df2[j >> 1].x;
        if (d2s <= dfs) {                  // certified screen -> exact f64
          const float pxs = px2[j >> 1][j & 1];
          const float pys = py2[j >> 1][j & 1];
          const float pzs = pz2[j >> 1][j & 1];
          double dx = __dsub_rn((double)pxs, (double)cxf);
          double dy = __dsub_rn((double)pys, (double)cyf);
          double dz = __dsub_rn((double)pzs, (double)czf);
          double d = __dadd_rn(__dadd_rn(__dmul_rn(dx, dx), __dmul_rn(dy, dy)),
                               __dmul_rn(dz, dz));
          if (d < dist[j]) {
            dist[j] = d;
            const float dfn = (float)d * 1.000002f;  // certified upper bound
            if (j & 1) df2[j >> 1].y = dfn; else df2[j >> 1].x = dfn;
            changed = true;
          }
        }
      }
      if (changed) {                       // rescan local max + refresh lmax
        lv = -1.0;
        li = 0;
#pragma unroll
        for (int j = 0; j < 8; ++j) {
          if (dist[j] > lv) { lv = dist[j]; li = tid + j * 1024; }  // j asc => min idx on tie
        }
        lv32 = (float)lv;
        lmax = fmaxf(fmaxf(fmaxf(df2[0].x, df2[0].y), fmaxf(df2[1].x, df2[1].y)),
                     fmaxf(fmaxf(df2[2].x, df2[2].y), fmaxf(df2[3].x, df2[3].y)));
      }
    }
    // wave f32 max needs recompute only if a former top lane changed
    const unsigned long long topChanged = __ballot(changed && wasTop);
    if (topChanged) {
      float m32 = lv32;
#pragma unroll
      for (int off = 1; off < 64; off <<= 1) m32 = fmaxf(m32, __shfl_xor(m32, off));
      wv32_c = m32;
    }
    const int pb = i & 1;
    // candidate lanes (contain the exact f64 wave max by monotonicity)
    if (lv32 == wv32_c) atomicMax(&slotV[pb], (unsigned long long)__double_as_longlong(lv));
    __syncthreads();
    const double W = __longlong_as_double((long long)slotV[pb]);
    if (lv == W) atomicMin(&slotI[pb], li);
    if (tid == 0) {                        // reset other parity for iter i+1
      slotV[pb ^ 1] = 0ull;
      slotI[pb ^ 1] = 0x7fffffff;
    }
    __syncthreads();
    cur = slotI[pb];
  }
  __syncthreads();
  // final gather: new_xyz[i][c] = lx[sidx[i]*3 + c]
  float* nxb = new_xyz + (size_t)b * Ss * 3;
  for (int e = tid; e < Ss * 3; e += 1024) {
    const int i = e / 3, c = e - i * 3;
    nxb[e] = lx[sidx[i] * 3 + c];
  }
}

// ---------------------------------------------------------------------------
// Ball query, both scales fused. One wave per center. f32 distances with a
// certified band fallback: decide in f32 unless |d2f - R^2| within 1e-5 rel
// (f32 error <= ~6e-7 rel), where the exact f64 compare (the r1-r11 passing
// semantics) runs. First nsample in-range points in original order; pad with
// first hit (0 if none).
// ---------------------------------------------------------------------------
__global__ __launch_bounds__(256) void ballq_kernel(const float* __restrict__ xyz,
                                                    const float* __restrict__ nxyz,
                                                    int* __restrict__ idx0,
                                                    int* __restrict__ idx1) {
  const int wid = threadIdx.x >> 6, lane = threadIdx.x & 63;
  const int bs = blockIdx.x * 4 + wid;
  const int b = bs >> 11;  // S = 2048
  const float* xb = xyz + (size_t)b * Nn * 3;
  const float cxf = nxyz[bs * 3 + 0];
  const float cyf = nxyz[bs * 3 + 1];
  const float czf = nxyz[bs * 3 + 2];
  const double R0d = 0.4 * 0.4, R1d = 0.8 * 0.8;   // exact doubles
  const float R0lo = 0.16f * (1.0f - 1e-5f), R0hi = 0.16f * (1.0f + 1e-5f);
  const float R1lo = 0.64f * (1.0f - 1e-5f), R1hi = 0.64f * (1.0f + 1e-5f);
  int cnt0 = 0, cnt1 = 0, first0 = 0, first1 = 0;
  const unsigned long long lmask = (1ull << lane) - 1ull;
  for (int base = 0; base < Nn; base += 64) {
    const int p = base + lane;
    const float pxs = xb[p * 3 + 0], pys = xb[p * 3 + 1], pzs = xb[p * 3 + 2];
    const float dxf = pxs - cxf, dyf = pys - cyf, dzf = pzs - czf;
    const float d2f = fmaf(dxf, dxf, fmaf(dyf, dyf, dzf * dzf));
    bool in0, in1;
    if (d2f < R0lo) in0 = true;
    else if (d2f > R0hi) in0 = false;
    else {  // certified band: exact f64 (rare)
      double dx = __dsub_rn((double)pxs, (double)cxf);
      double dy = __dsub_rn((double)pys, (double)cyf);
      double dz = __dsub_rn((double)pzs, (double)czf);
      double d2 = __dadd_rn(__dadd_rn(__dmul_rn(dx, dx), __dmul_rn(dy, dy)), __dmul_rn(dz, dz));
      in0 = d2 < R0d;
    }
    if (d2f < R1lo) in1 = true;
    else if (d2f > R1hi) in1 = false;
    else {
      double dx = __dsub_rn((double)pxs, (double)cxf);
      double dy = __dsub_rn((double)pys, (double)cyf);
      double dz = __dsub_rn((double)pzs, (double)czf);
      double d2 = __dadd_rn(__dadd_rn(__dmul_rn(dx, dx), __dmul_rn(dy, dy)), __dmul_rn(dz, dz));
      in1 = d2 < R1d;
    }
    unsigned long long m0 = __ballot(in0);
    unsigned long long m1 = __ballot(in1);
    if (cnt0 < 16 && m0) {
      if (cnt0 == 0) first0 = base + __builtin_ctzll(m0);
      int r = (int)__popcll(m0 & lmask);
      if (in0 && cnt0 + r < 16) idx0[bs * 16 + cnt0 + r] = p;
      cnt0 += (int)__popcll(m0);
    }
    if (cnt1 < 32 && m1) {
      if (cnt1 == 0) first1 = base + __builtin_ctzll(m1);
      int r = (int)__popcll(m1 & lmask);
      if (in1 && cnt1 + r < 32) idx1[bs * 32 + cnt1 + r] = p;
      cnt1 += (int)__popcll(m1);
    }
    if (cnt0 >= 16 && cnt1 >= 32) break;
  }
  const int f0 = cnt0 < 16 ? cnt0 : 16;
  for (int j = f0 + lane; j < 16; j += 64) idx0[bs * 16 + j] = first0;
  const int f1 = cnt1 < 32 ? cnt1 : 32;
  for (int j = f1 + lane; j < 32; j += 64) idx1[bs * 32 + j] = first1;
}

// ---------------------------------------------------------------------------
// Generic tall-skinny GEMM with fused input transforms and striped BN-stat
// atomics. Tile: 64 rows x COUT, 256 threads, 4 rows x (COUT/16) cols each.
// MODE 0: gather (rel-xyz ++ features) via ball-query idx          (K=67)
// MODE 1: x = relu(bn(prev_raw)) from 64-ch buffer (in-place safe) (K=64)
// MODE 2: x = concat(relu(bn(pool0)), relu(bn(pool1)))             (K=256)
// MODE 4: x = relu(bn(xin)) from 256-ch buffer; also writes x to hw (K=256)
// BN stats arrive as striped raw sums [sum(C)xNSL | sumsq(C)xNSL]; mu/rstd
// computed inline into LDS. Epilogue atomicAdds per-channel (sum, sumsq)
// into stripe slot (blockIdx & 31) -> contention/address = gridX/32.
// POOL: write per-group (NS) max of raw output instead of full rows.
// ---------------------------------------------------------------------------
template <int COUT, int KTOT, int MODE, int NS, bool POOL, bool BIAS>
__global__ __launch_bounds__(256) void mlp_gemm(
    const float* __restrict__ xin, const float* __restrict__ xin2,
    const float* __restrict__ stIn, const float* __restrict__ stIn2,
    float invM1, float invM2,
    const float* __restrict__ w, const float* __restrict__ bias,
    const int* __restrict__ gidx, const float* __restrict__ xyz,
    const float* __restrict__ nxyz, const float* __restrict__ feats,
    float* __restrict__ hw, float* __restrict__ out, float* __restrict__ Sout) {
  constexpr int KC = (KTOT <= 68) ? KTOT : 32;     // K chunk
  constexpr int NCH = (KTOT + KC - 1) / KC;
  constexpr int TC = COUT / 16;                    // cols per thread
  constexpr int XPAD = KC + 1;
  constexpr int XSZ = 64 * XPAD;
  constexpr int EPI = (POOL ? 48 : 32) * COUT;
  constexpr int SM = (XSZ + KC * COUT > EPI) ? (XSZ + KC * COUT) : EPI;
  constexpr int BNSZ = (MODE == 0) ? 0 : 512;
  __shared__ float smem[SM + BNSZ];
  float* xS = smem;
  float* wS = smem + XSZ;
  float* bnM = smem + SM;                  // persists (outside reused region)
  float* bnR = smem + SM + 256;

  const int tid = threadIdx.x;
  const int cg = tid & 15, rg = tid >> 4;
  const int row0 = blockIdx.x * 64;

  if constexpr (MODE != 0) {               // inline BN finalize (striped sums)
    for (int c = tid; c < KTOT; c += 256) {
      float sum = 0.f, sq = 0.f, im;
      if constexpr (MODE == 2) {
        const float* base = (c < 128) ? stIn : stIn2;
        const int cc = (c < 128) ? c : c - 128;
        im = (c < 128) ? invM1 : invM2;
#pragma unroll
        for (int s = 0; s < NSL; ++s) {
          sum += base[cc * NSL + s];
          sq += base[(128 + cc) * NSL + s];
        }
      } else {
        constexpr int C = (MODE == 1) ? 64 : 256;
        im = invM1;
#pragma unroll
        for (int s = 0; s < NSL; ++s) {
          sum += stIn[c * NSL + s];
          sq += stIn[(C + c) * NSL + s];
        }
      }
      const float mu = sum * im;
      const float var = sq * im - mu * mu;
      bnM[c] = mu;
      bnR[c] = 1.0f / sqrtf(var + 1e-5f);
    }
    __syncthreads();
  }

  float acc[4][TC];
#pragma unroll
  for (int i = 0; i < 4; ++i)
#pragma unroll
    for (int t = 0; t < TC; ++t) acc[i][t] = 0.f;

  for (int ch = 0; ch < NCH; ++ch) {
    const int k0 = ch * KC;
    if (ch) __syncthreads();
    // ---- stage x tile [64 rows][KC] (row-major, padded) ----
    for (int e = tid; e < 64 * KC; e += 256) {
      const int r = e / KC, kk = e - r * KC;
      const int kg = k0 + kk;
      const int rowg = row0 + r;
      float v;
      if constexpr (MODE == 0) {
        const int bs = rowg / NS;
        const int p = gidx[rowg];
        const int bb = bs >> 11;
        if (kg < 3)
          v = xyz[(bb * Nn + p) * 3 + kg] - nxyz[bs * 3 + kg];
        else
          v = feats[((bb * Nn + p) << 6) + (kg - 3)];
      } else if constexpr (MODE == 1) {
        v = fmaxf((xin[(size_t)rowg * 64 + kg] - bnM[kg]) * bnR[kg], 0.f);
      } else if constexpr (MODE == 2) {
        if (kg < 128)
          v = fmaxf((xin[(size_t)rowg * 128 + kg] - bnM[kg]) * bnR[kg], 0.f);
        else
          v = fmaxf((xin2[(size_t)rowg * 128 + (kg - 128)] - bnM[kg]) * bnR[kg], 0.f);
      } else {  // MODE 4
        v = fmaxf((xin[(size_t)rowg * 256 + kg] - bnM[kg]) * bnR[kg], 0.f);
        hw[(size_t)rowg * 256 + kg] = v;
      }
      xS[r * XPAD + kk] = v;
    }
    // ---- stage w chunk [KC][COUT] ----
    for (int e = tid; e < KC * COUT; e += 256) {
      const int kk = e / COUT, c = e - kk * COUT;
      wS[kk * COUT + c] = w[(size_t)(k0 + kk) * COUT + c];
    }
    __syncthreads();
    // ---- FMA loop ----
    for (int kk = 0; kk < KC; ++kk) {
      float xr[4];
#pragma unroll
      for (int i = 0; i < 4; ++i) xr[i] = xS[(rg * 4 + i) * XPAD + kk];
#pragma unroll
      for (int t = 0; t < TC; t += 4) {
        const float4 wv = *(const float4*)&wS[kk * COUT + cg * TC + t];
#pragma unroll
        for (int i = 0; i < 4; ++i) {
          acc[i][t + 0] = fmaf(xr[i], wv.x, acc[i][t + 0]);
          acc[i][t + 1] = fmaf(xr[i], wv.y, acc[i][t + 1]);
          acc[i][t + 2] = fmaf(xr[i], wv.z, acc[i][t + 2]);
          acc[i][t + 3] = fmaf(xr[i], wv.w, acc[i][t + 3]);
        }
      }
    }
  }
  __syncthreads();  // smem reuse below
  if constexpr (BIAS) {
#pragma unroll
    for (int t = 0; t < TC; ++t) {
      const float bv = bias[cg * TC + t];
#pragma unroll
      for (int i = 0; i < 4; ++i) acc[i][t] += bv;
    }
  }
  // ---- per-block BN partials (+ group max for POOL) ----
  float* ssum = smem;
  float* ssq = smem + 16 * COUT;
  float* pbuf = smem + 32 * COUT;
  const int colb = cg * TC;
#pragma unroll
  for (int t = 0; t < TC; ++t) {
    float s = 0.f, q = 0.f, m = -3.4e38f;
#pragma unroll
    for (int i = 0; i < 4; ++i) {
      const float v = acc[i][t];
      s += v;
      q = fmaf(v, v, q);
      m = fmaxf(m, v);
    }
    ssum[rg * COUT + colb + t] = s;
    ssq[rg * COUT + colb + t] = q;
    if constexpr (POOL) pbuf[rg * COUT + colb + t] = m;
  }
  __syncthreads();
  const int slot = blockIdx.x & (NSL - 1);
  for (int c = tid; c < COUT; c += 256) {
    float s = 0.f, q = 0.f;
#pragma unroll
    for (int rr = 0; rr < 16; ++rr) {
      s += ssum[rr * COUT + c];
      q += ssq[rr * COUT + c];
    }
    atomicAdd(&Sout[c * NSL + slot], s);
    atomicAdd(&Sout[(COUT + c) * NSL + slot], q);
  }
  if constexpr (POOL) {
    constexpr int G = 64 / NS, RPG = NS / 4;
    for (int o = tid; o < G * COUT; o += 256) {
      const int g = o / COUT, c = o - g * COUT;
      float m = pbuf[(g * RPG) * COUT + c];
#pragma unroll
      for (int qq = 1; qq < RPG; ++qq) m = fmaxf(m, pbuf[(g * RPG + qq) * COUT + c]);
      out[(size_t)(blockIdx.x * G + g) * COUT + c] = m;
    }
  } else {
#pragma unroll
    for (int i = 0; i < 4; ++i) {
      float* op = out + (size_t)(row0 + rg * 4 + i) * COUT + colb;
#pragma unroll
      for (int t = 0; t < TC; t += 4) {
        *(float4*)(op + t) = make_float4(acc[i][t], acc[i][t + 1], acc[i][t + 2], acc[i][t + 3]);
      }
    }
  }
}

// cls = relu(bn(conf_raw)) @ cls_w + cls_b   (one wave per row; inline BN)
__global__ __launch_bounds__(256) void cls_kernel(const float* __restrict__ craw,
                                                  const float* __restrict__ st,
                                                  const float* __restrict__ clsw,
                                                  const float* __restrict__ clsb,
                                                  float* __restrict__ outc) {
  __shared__ float bnM[256], bnR[256];
  const int tid = threadIdx.x;
  {
    float sum = 0.f, sq = 0.f;
#pragma unroll
    for (int s = 0; s < NSL; ++s) {
      sum += st[tid * NSL + s];
      sq += st[(256 + tid) * NSL + s];
    }
    const float im = 1.0f / 16384.0f;
    const float mu = sum * im;
    const float var = sq * im - mu * mu;
    bnM[tid] = mu;
    bnR[tid] = 1.0f / sqrtf(var + 1e-5f);
  }
  __syncthreads();
  const int wid = tid >> 6, lane = tid & 63;
  const int row = blockIdx.x * 4 + wid;
  const float* cr = craw + (size_t)row * 256;
  float a0 = 0.f, a1 = 0.f, a2 = 0.f;
#pragma unroll 4
  for (int k = lane; k < 256; k += 64) {
    float x = fmaxf((cr[k] - bnM[k]) * bnR[k], 0.f);
    a0 = fmaf(x, clsw[k * 3 + 0], a0);
    a1 = fmaf(x, clsw[k * 3 + 1], a1);
    a2 = fmaf(x, clsw[k * 3 + 2], a2);
  }
#pragma unroll
  for (int off = 32; off; off >>= 1) {
    a0 += __shfl_down(a0, off);
    a1 += __shfl_down(a1, off);
    a2 += __shfl_down(a2, off);
  }
  if (lane == 0) {
    outc[row * 3 + 0] = a0 + clsb[0];
    outc[row * 3 + 1] = a1 + clsb[1];
    outc[row * 3 + 2] = a2 + clsb[2];
  }
}

// ---------------------------------------------------------------------------
extern "C" void kernel_launch(void* const* d_in, const int* in_sizes, int n_in,
                              void* d_out, int out_size, void* d_ws, size_t ws_size,
                              hipStream_t stream) {
  (void)in_sizes; (void)n_in; (void)out_size; (void)ws_size;
  const float* xyz = (const float*)d_in[0];
  const float* feats = (const float*)d_in[1];
  const float* w00 = (const float*)d_in[2];
  const float* w01 = (const float*)d_in[3];
  const float* w02 = (const float*)d_in[4];
  const float* w10 = (const float*)d_in[5];
  const float* w11 = (const float*)d_in[6];
  const float* w12 = (const float*)d_in[7];
  const float* aggw = (const float*)d_in[8];
  const float* aggb = (const float*)d_in[9];
  const float* confw = (const float*)d_in[10];
  const float* clsw = (const float*)d_in[11];
  const float* clsb = (const float*)d_in[12];

  float* outp = (float*)d_out;
  float* nxyz = outp;                               // [BS,3]
  float* hout = outp + (size_t)BS * 3;              // [BS,256]
  float* clsout = hout + (size_t)BS * 256;          // [BS,3]

  char* ws = (char*)d_ws;
  const size_t MB = 1u << 20;
  int* idx0 = (int*)(ws + 0);                       // 1 MB
  int* idx1 = (int*)(ws + 1 * MB);                  // 2 MB
  float* st = (float*)(ws + 3 * MB);                // striped BN stats: 64K floats
  float* pool0 = (float*)(ws + 12 * MB);            // [BS,128]
  float* pool1 = (float*)(ws + 20 * MB);            // [BS,128]
  float* aggraw = (float*)(ws + 28 * MB);           // [BS,256]
  float* confraw = (float*)(ws + 44 * MB);          // [BS,256]
  float* hA = (float*)(ws + 60 * MB);               // [524288,64] (layers 1/2 in-place)

  // striped stats offsets (floats, NSL=32):
  // s0L1=0 s0L2=4096 s0L3=8192 s1L1=16384 s1L2=20480 s1L3=24576
  // agg=32768 conf=49152 ; total 65536 floats
  hipMemsetAsync(st, 0, 65536 * sizeof(float), stream);

  const float iM0 = 1.0f / 262144.0f;   // scale0 rows
  const float iM1 = 1.0f / 524288.0f;   // scale1 rows
  const float iMh = 1.0f / 16384.0f;    // BS rows

  fps_kernel<<<Bb, 1024, 0, stream>>>(xyz, nxyz);
  ballq_kernel<<<BS / 4, 256, 0, stream>>>(xyz, nxyz, idx0, idx1);

  // ---- scale 0 (r=0.4, ns=16) ----
  mlp_gemm<64, 67, 0, 16, false, false><<<4096, 256, 0, stream>>>(
      nullptr, nullptr, nullptr, nullptr, 0.f, 0.f, w00, nullptr,
      idx0, xyz, nxyz, feats, nullptr, hA, st + 0);
  mlp_gemm<64, 64, 1, 1, false, false><<<4096, 256, 0, stream>>>(
      hA, nullptr, st + 0, nullptr, iM0, 0.f, w01, nullptr,
      nullptr, nullptr, nullptr, nullptr, nullptr, hA, st + 4096);
  mlp_gemm<128, 64, 1, 16, true, false><<<4096, 256, 0, stream>>>(
      hA, nullptr, st + 4096, nullptr, iM0, 0.f, w02, nullptr,
      nullptr, nullptr, nullptr, nullptr, nullptr, pool0, st + 8192);

  // ---- scale 1 (r=0.8, ns=32) ----
  mlp_gemm<64, 67, 0, 32, false, false><<<8192, 256, 0, stream>>>(
      nullptr, nullptr, nullptr, nullptr, 0.f, 0.f, w10, nullptr,
      idx1, xyz, nxyz, feats, nullptr, hA, st + 16384);
  mlp_gemm<64, 64, 1, 1, false, false><<<8192, 256, 0, stream>>>(
      hA, nullptr, st + 16384, nullptr, iM1, 0.f, w11, nullptr,
      nullptr, nullptr, nullptr, nullptr, nullptr, hA, st + 20480);
  mlp_gemm<128, 64, 1, 32, true, false><<<8192, 256, 0, stream>>>(
      hA, nullptr, st + 20480, nullptr, iM1, 0.f, w12, nullptr,
      nullptr, nullptr, nullptr, nullptr, nullptr, pool1, st + 24576);

  // ---- aggregation: concat(bn3_0(pool0), bn3_1(pool1)) @ agg_w + agg_b ----
  mlp_gemm<256, 256, 2, 1, false, true><<<256, 256, 0, stream>>>(
      pool0, pool1, st + 8192, st + 24576, iM0, iM1, aggw, aggb,
      nullptr, nullptr, nullptr, nullptr, nullptr, aggraw, st + 32768);

  // ---- confidence hidden layer (MODE 4: bn+relu(aggraw) -> h to d_out,
  //      GEMM against conf_w) ----
  mlp_gemm<256, 256, 4, 1, false, false><<<256, 256, 0, stream>>>(
      aggraw, nullptr, st + 32768, nullptr, iMh, 0.f, confw, nullptr,
      nullptr, nullptr, nullptr, nullptr, hout, confraw, st + 49152);

  // ---- classifier ----
  cls_kernel<<<BS / 4, 256, 0, stream>>>(confraw, st + 49152, clsw, clsb, clsout);
}

// Round 13
// 3684.195 us; speedup vs baseline: 1.0746x; 1.0050x over previous
//
#include <hip/hip_runtime.h>
#include <cstdint>
#include <cstddef>

// Problem constants (fixed by reference setup_inputs)
constexpr int Bb = 8;
constexpr int Nn = 8192;
constexpr int Ss = 2048;
constexpr int BS = Bb * Ss;  // 16384
constexpr int NSL = 32;      // BN-stat atomic stripe count

typedef float vfloat2 __attribute__((ext_vector_type(2)));

// ---------------------------------------------------------------------------
// FPS: one block per batch, 1024 threads, 8 points/thread (proven shape).
// dist[] updates exact f64 (bit-matches np, verified r1-r12); certified f32
// screening skips only provable non-updates. Exact atomic reduce (r10) +
// wasTop-gated wave max refresh (r11). Unchanged from r11/r12 (~2502 us —
// structural floor for this serial algorithm; 7 reduce variants all >=2500).
// ---------------------------------------------------------------------------
__global__ __launch_bounds__(1024) void fps_kernel(const float* __restrict__ xyz,
                                                   float* __restrict__ new_xyz) {
  __shared__ float lx[Nn * 3];             // 96 KB: batch point cloud
  __shared__ int sidx[Ss];                 // 8 KB: selected-index log
  __shared__ unsigned long long slotV[2];  // parity: f64-bit global max
  __shared__ int slotI[2];                 // parity: winner index (min over ties)
  const int b = blockIdx.x;
  const int tid = threadIdx.x;
  const float* xb = xyz + (size_t)b * Nn * 3;
  for (int e = tid; e < Nn * 3; e += 1024) lx[e] = xb[e];
  if (tid == 0) {
    slotV[0] = 0ull; slotV[1] = 0ull;
    slotI[0] = 0x7fffffff; slotI[1] = 0x7fffffff;
  }
  __syncthreads();

  vfloat2 px2[4], py2[4], pz2[4], df2[4];
  double dist[8];
#pragma unroll
  for (int jj = 0; jj < 4; ++jj) {
    const int p0 = tid + (2 * jj) * 1024, p1 = tid + (2 * jj + 1) * 1024;
    px2[jj] = (vfloat2){lx[p0 * 3 + 0], lx[p1 * 3 + 0]};
    py2[jj] = (vfloat2){lx[p0 * 3 + 1], lx[p1 * 3 + 1]};
    pz2[jj] = (vfloat2){lx[p0 * 3 + 2], lx[p1 * 3 + 2]};
    df2[jj] = (vfloat2){3.0e38f, 3.0e38f};   // force exact path on first touch
    dist[2 * jj] = 1e10;
    dist[2 * jj + 1] = 1e10;
  }
  float lmax = 3.0e38f;                    // cached max of certified bounds
  int cur = 0;
  double lv = -1.0;                        // per-lane cached local max (exact)
  int li = 0x7fffffff;
  float lv32 = -1.0f;                      // cached (float)lv
  float wv32_c = -1.0f;                    // cached wave f32 max
  for (int i = 0; i < Ss; ++i) {
    if (tid == 0) sidx[i] = cur;           // LDS log (visible after barrier)
    const float cxf = lx[cur * 3 + 0], cyf = lx[cur * 3 + 1], czf = lx[cur * 3 + 2];
    const vfloat2 cx2 = {cxf, cxf}, cy2 = {cyf, cyf}, cz2 = {czf, czf};
    const bool wasTop = (lv32 == wv32_c);  // latched BEFORE updates
    // ---- packed-f32 distances ----
    vfloat2 d2v[4];
#pragma unroll
    for (int jj = 0; jj < 4; ++jj) {
      const vfloat2 dx = px2[jj] - cx2;
      const vfloat2 dy = py2[jj] - cy2;
      const vfloat2 dz = pz2[jj] - cz2;
      d2v[jj] = dx * dx + dy * dy + dz * dz;
    }
    const float dmin = fminf(fminf(fminf(d2v[0].x, d2v[0].y), fminf(d2v[1].x, d2v[1].y)),
                             fminf(fminf(d2v[2].x, d2v[2].y), fminf(d2v[3].x, d2v[3].y)));
    bool changed = false;
    if (dmin <= lmax) {                    // necessary condition for any update
#pragma unroll
      for (int j = 0; j < 8; ++j) {
        const float d2s = d2v[j >> 1][j & 1];
        const float dfs = (j & 1) ? df2[j >> 1].y : df2[j >> 1].x;
        if (d2s <= dfs) {                  // certified screen -> exact f64
          const float pxs = px2[j >> 1][j & 1];
          const float pys = py2[j >> 1][j & 1];
          const float pzs = pz2[j >> 1][j & 1];
          double dx = __dsub_rn((double)pxs, (double)cxf);
          double dy = __dsub_rn((double)pys, (double)cyf);
          double dz = __dsub_rn((double)pzs, (double)czf);
          double d = __dadd_rn(__dadd_rn(__dmul_rn(dx, dx), __dmul_rn(dy, dy)),
                               __dmul_rn(dz, dz));
          if (d < dist[j]) {
            dist[j] = d;
            const float dfn = (float)d * 1.000002f;  // certified upper bound
            if (j & 1) df2[j >> 1].y = dfn; else df2[j >> 1].x = dfn;
            changed = true;
          }
        }
      }
      if (changed) {                       // rescan local max + refresh lmax
        lv = -1.0;
        li = 0;
#pragma unroll
        for (int j = 0; j < 8; ++j) {
          if (dist[j] > lv) { lv = dist[j]; li = tid + j * 1024; }  // j asc => min idx on tie
        }
        lv32 = (float)lv;
        lmax = fmaxf(fmaxf(fmaxf(df2[0].x, df2[0].y), fmaxf(df2[1].x, df2[1].y)),
                     fmaxf(fmaxf(df2[2].x, df2[2].y), fmaxf(df2[3].x, df2[3].y)));
      }
    }
    // wave f32 max needs recompute only if a former top lane changed
    const unsigned long long topChanged = __ballot(changed && wasTop);
    if (topChanged) {
      float m32 = lv32;
#pragma unroll
      for (int off = 1; off < 64; off <<= 1) m32 = fmaxf(m32, __shfl_xor(m32, off));
      wv32_c = m32;
    }
    const int pb = i & 1;
    // candidate lanes (contain the exact f64 wave max by monotonicity)
    if (lv32 == wv32_c) atomicMax(&slotV[pb], (unsigned long long)__double_as_longlong(lv));
    __syncthreads();
    const double W = __longlong_as_double((long long)slotV[pb]);
    if (lv == W) atomicMin(&slotI[pb], li);
    if (tid == 0) {                        // reset other parity for iter i+1
      slotV[pb ^ 1] = 0ull;
      slotI[pb ^ 1] = 0x7fffffff;
    }
    __syncthreads();
    cur = slotI[pb];
  }
  __syncthreads();
  // final gather: new_xyz[i][c] = lx[sidx[i]*3 + c]
  float* nxb = new_xyz + (size_t)b * Ss * 3;
  for (int e = tid; e < Ss * 3; e += 1024) {
    const int i = e / 3, c = e - i * 3;
    nxb[e] = lx[sidx[i] * 3 + c];
  }
}

// ---------------------------------------------------------------------------
// Ball query, both scales fused. One wave per center. f32 distances with a
// certified band fallback (exact f64 inside the band). First nsample in-range
// points in original order; pad with first hit (0 if none). (r12, passing.)
// ---------------------------------------------------------------------------
__global__ __launch_bounds__(256) void ballq_kernel(const float* __restrict__ xyz,
                                                    const float* __restrict__ nxyz,
                                                    int* __restrict__ idx0,
                                                    int* __restrict__ idx1) {
  const int wid = threadIdx.x >> 6, lane = threadIdx.x & 63;
  const int bs = blockIdx.x * 4 + wid;
  const int b = bs >> 11;  // S = 2048
  const float* xb = xyz + (size_t)b * Nn * 3;
  const float cxf = nxyz[bs * 3 + 0];
  const float cyf = nxyz[bs * 3 + 1];
  const float czf = nxyz[bs * 3 + 2];
  const double R0d = 0.4 * 0.4, R1d = 0.8 * 0.8;   // exact doubles
  const float R0lo = 0.16f * (1.0f - 1e-5f), R0hi = 0.16f * (1.0f + 1e-5f);
  const float R1lo = 0.64f * (1.0f - 1e-5f), R1hi = 0.64f * (1.0f + 1e-5f);
  int cnt0 = 0, cnt1 = 0, first0 = 0, first1 = 0;
  const unsigned long long lmask = (1ull << lane) - 1ull;
  for (int base = 0; base < Nn; base += 64) {
    const int p = base + lane;
    const float pxs = xb[p * 3 + 0], pys = xb[p * 3 + 1], pzs = xb[p * 3 + 2];
    const float dxf = pxs - cxf, dyf = pys - cyf, dzf = pzs - czf;
    const float d2f = fmaf(dxf, dxf, fmaf(dyf, dyf, dzf * dzf));
    bool in0, in1;
    if (d2f < R0lo) in0 = true;
    else if (d2f > R0hi) in0 = false;
    else {  // certified band: exact f64 (rare)
      double dx = __dsub_rn((double)pxs, (double)cxf);
      double dy = __dsub_rn((double)pys, (double)cyf);
      double dz = __dsub_rn((double)pzs, (double)czf);
      double d2 = __dadd_rn(__dadd_rn(__dmul_rn(dx, dx), __dmul_rn(dy, dy)), __dmul_rn(dz, dz));
      in0 = d2 < R0d;
    }
    if (d2f < R1lo) in1 = true;
    else if (d2f > R1hi) in1 = false;
    else {
      double dx = __dsub_rn((double)pxs, (double)cxf);
      double dy = __dsub_rn((double)pys, (double)cyf);
      double dz = __dsub_rn((double)pzs, (double)czf);
      double d2 = __dadd_rn(__dadd_rn(__dmul_rn(dx, dx), __dmul_rn(dy, dy)), __dmul_rn(dz, dz));
      in1 = d2 < R1d;
    }
    unsigned long long m0 = __ballot(in0);
    unsigned long long m1 = __ballot(in1);
    if (cnt0 < 16 && m0) {
      if (cnt0 == 0) first0 = base + __builtin_ctzll(m0);
      int r = (int)__popcll(m0 & lmask);
      if (in0 && cnt0 + r < 16) idx0[bs * 16 + cnt0 + r] = p;
      cnt0 += (int)__popcll(m0);
    }
    if (cnt1 < 32 && m1) {
      if (cnt1 == 0) first1 = base + __builtin_ctzll(m1);
      int r = (int)__popcll(m1 & lmask);
      if (in1 && cnt1 + r < 32) idx1[bs * 32 + cnt1 + r] = p;
      cnt1 += (int)__popcll(m1);
    }
    if (cnt0 >= 16 && cnt1 >= 32) break;
  }
  const int f0 = cnt0 < 16 ? cnt0 : 16;
  for (int j = f0 + lane; j < 16; j += 64) idx0[bs * 16 + j] = first0;
  const int f1 = cnt1 < 32 ? cnt1 : 32;
  for (int j = f1 + lane; j < 32; j += 64) idx1[bs * 32 + j] = first1;
}

// ---------------------------------------------------------------------------
// Generic tall-skinny GEMM with fused input transforms and striped BN-stat
// atomics. Tile: 64 rows x COUT, 256 threads, 4 rows x (COUT/16) cols each.
// Round-13: packed vfloat2 accumulators (v_pk_fma_f32, 2x f32 issue rate;
// pairing is across output columns so per-element accumulation order — and
// thus results — are bit-identical), and MODE-0 row cache (point offsets +
// center coords staged to LDS once, killing redundant gidx/nxyz loads).
// MODE 0: gather (rel-xyz ++ features) via ball-query idx          (K=67)
// MODE 1: x = relu(bn(prev_raw)) from 64-ch buffer (in-place safe) (K=64)
// MODE 2: x = concat(relu(bn(pool0)), relu(bn(pool1)))             (K=256)
// MODE 4: x = relu(bn(xin)) from 256-ch buffer; also writes x to hw (K=256)
// ---------------------------------------------------------------------------
template <int COUT, int KTOT, int MODE, int NS, bool POOL, bool BIAS>
__global__ __launch_bounds__(256) void mlp_gemm(
    const float* __restrict__ xin, const float* __restrict__ xin2,
    const float* __restrict__ stIn, const float* __restrict__ stIn2,
    float invM1, float invM2,
    const float* __restrict__ w, const float* __restrict__ bias,
    const int* __restrict__ gidx, const float* __restrict__ xyz,
    const float* __restrict__ nxyz, const float* __restrict__ feats,
    float* __restrict__ hw, float* __restrict__ out, float* __restrict__ Sout) {
  constexpr int KC = (KTOT <= 68) ? KTOT : 32;     // K chunk
  constexpr int NCH = (KTOT + KC - 1) / KC;
  constexpr int TC = COUT / 16;                    // cols per thread
  constexpr int TC2 = TC / 2;                      // packed col pairs
  constexpr int XPAD = KC + 1;
  constexpr int XSZ = 64 * XPAD;
  constexpr int EPI = (POOL ? 48 : 32) * COUT;
  constexpr int SM = (XSZ + KC * COUT > EPI) ? (XSZ + KC * COUT) : EPI;
  constexpr int BNSZ = (MODE == 0) ? 0 : 512;
  __shared__ float smem[SM + BNSZ];
  __shared__ int rowP[(MODE == 0) ? 64 : 1];       // MODE0: gathered point offset
  __shared__ float rowC[(MODE == 0) ? 192 : 1];    // MODE0: center coords
  float* xS = smem;
  float* wS = smem + XSZ;
  float* bnM = smem + SM;                  // persists (outside reused region)
  float* bnR = smem + SM + 256;

  const int tid = threadIdx.x;
  const int cg = tid & 15, rg = tid >> 4;
  const int row0 = blockIdx.x * 64;

  if constexpr (MODE == 0) {               // row cache: one gidx load per row
    if (tid < 64) {
      const int rowg = row0 + tid;
      const int bs = rowg / NS;
      const int bb = bs >> 11;
      rowP[tid] = bb * Nn + gidx[rowg];
      rowC[tid * 3 + 0] = nxyz[bs * 3 + 0];
      rowC[tid * 3 + 1] = nxyz[bs * 3 + 1];
      rowC[tid * 3 + 2] = nxyz[bs * 3 + 2];
    }
    __syncthreads();
  } else {                                 // inline BN finalize (striped sums)
    for (int c = tid; c < KTOT; c += 256) {
      float sum = 0.f, sq = 0.f, im;
      if constexpr (MODE == 2) {
        const float* base = (c < 128) ? stIn : stIn2;
        const int cc = (c < 128) ? c : c - 128;
        im = (c < 128) ? invM1 : invM2;
#pragma unroll
        for (int s = 0; s < NSL; ++s) {
          sum += base[cc * NSL + s];
          sq += base[(128 + cc) * NSL + s];
        }
      } else {
        constexpr int C = (MODE == 1) ? 64 : 256;
        im = invM1;
#pragma unroll
        for (int s = 0; s < NSL; ++s) {
          sum += stIn[c * NSL + s];
          sq += stIn[(C + c) * NSL + s];
        }
      }
      const float mu = sum * im;
      const float var = sq * im - mu * mu;
      bnM[c] = mu;
      bnR[c] = 1.0f / sqrtf(var + 1e-5f);
    }
    __syncthreads();
  }

  vfloat2 acc2[4][TC2];
#pragma unroll
  for (int i = 0; i < 4; ++i)
#pragma unroll
    for (int t = 0; t < TC2; ++t) acc2[i][t] = (vfloat2){0.f, 0.f};

  for (int ch = 0; ch < NCH; ++ch) {
    const int k0 = ch * KC;
    if (ch) __syncthreads();
    // ---- stage x tile [64 rows][KC] (row-major, padded) ----
    for (int e = tid; e < 64 * KC; e += 256) {
      const int r = e / KC, kk = e - r * KC;
      const int kg = k0 + kk;
      const int rowg = row0 + r;
      float v;
      if constexpr (MODE == 0) {
        if (kg < 3)
          v = xyz[rowP[r] * 3 + kg] - rowC[r * 3 + kg];
        else
          v = feats[(rowP[r] << 6) + (kg - 3)];
      } else if constexpr (MODE == 1) {
        v = fmaxf((xin[(size_t)rowg * 64 + kg] - bnM[kg]) * bnR[kg], 0.f);
      } else if constexpr (MODE == 2) {
        if (kg < 128)
          v = fmaxf((xin[(size_t)rowg * 128 + kg] - bnM[kg]) * bnR[kg], 0.f);
        else
          v = fmaxf((xin2[(size_t)rowg * 128 + (kg - 128)] - bnM[kg]) * bnR[kg], 0.f);
      } else {  // MODE 4
        v = fmaxf((xin[(size_t)rowg * 256 + kg] - bnM[kg]) * bnR[kg], 0.f);
        hw[(size_t)rowg * 256 + kg] = v;
      }
      xS[r * XPAD + kk] = v;
    }
    // ---- stage w chunk [KC][COUT] ----
    for (int e = tid; e < KC * COUT; e += 256) {
      const int kk = e / COUT, c = e - kk * COUT;
      wS[kk * COUT + c] = w[(size_t)(k0 + kk) * COUT + c];
    }
    __syncthreads();
    // ---- packed FMA loop (v_pk_fma_f32) ----
    for (int kk = 0; kk < KC; ++kk) {
      vfloat2 x2[4];
#pragma unroll
      for (int i = 0; i < 4; ++i) {
        const float xr = xS[(rg * 4 + i) * XPAD + kk];
        x2[i] = (vfloat2){xr, xr};
      }
#pragma unroll
      for (int t2 = 0; t2 < TC2; t2 += 2) {
        const float4 wv = *(const float4*)&wS[kk * COUT + cg * TC + 2 * t2];
        const vfloat2 w0 = {wv.x, wv.y}, w1 = {wv.z, wv.w};
#pragma unroll
        for (int i = 0; i < 4; ++i) {
          acc2[i][t2] += x2[i] * w0;
          acc2[i][t2 + 1] += x2[i] * w1;
        }
      }
    }
  }
  __syncthreads();  // smem reuse below
  if constexpr (BIAS) {
#pragma unroll
    for (int t = 0; t < TC; ++t) {
      const float bv = bias[cg * TC + t];
#pragma unroll
      for (int i = 0; i < 4; ++i) {
        if (t & 1) acc2[i][t >> 1].y += bv; else acc2[i][t >> 1].x += bv;
      }
    }
  }
  // ---- per-block BN partials (+ group max for POOL) ----
  float* ssum = smem;
  float* ssq = smem + 16 * COUT;
  float* pbuf = smem + 32 * COUT;
  const int colb = cg * TC;
#pragma unroll
  for (int t = 0; t < TC; ++t) {
    float s = 0.f, q = 0.f, m = -3.4e38f;
#pragma unroll
    for (int i = 0; i < 4; ++i) {
      const float v = (t & 1) ? acc2[i][t >> 1].y : acc2[i][t >> 1].x;
      s += v;
      q = fmaf(v, v, q);
      m = fmaxf(m, v);
    }
    ssum[rg * COUT + colb + t] = s;
    ssq[rg * COUT + colb + t] = q;
    if constexpr (POOL) pbuf[rg * COUT + colb + t] = m;
  }
  __syncthreads();
  const int slot = blockIdx.x & (NSL - 1);
  for (int c = tid; c < COUT; c += 256) {
    float s = 0.f, q = 0.f;
#pragma unroll
    for (int rr = 0; rr < 16; ++rr) {
      s += ssum[rr * COUT + c];
      q += ssq[rr * COUT + c];
    }
    atomicAdd(&Sout[c * NSL + slot], s);
    atomicAdd(&Sout[(COUT + c) * NSL + slot], q);
  }
  if constexpr (POOL) {
    constexpr int G = 64 / NS, RPG = NS / 4;
    for (int o = tid; o < G * COUT; o += 256) {
      const int g = o / COUT, c = o - g * COUT;
      float m = pbuf[(g * RPG) * COUT + c];
#pragma unroll
      for (int qq = 1; qq < RPG; ++qq) m = fmaxf(m, pbuf[(g * RPG + qq) * COUT + c]);
      out[(size_t)(blockIdx.x * G + g) * COUT + c] = m;
    }
  } else {
#pragma unroll
    for (int i = 0; i < 4; ++i) {
      float* op = out + (size_t)(row0 + rg * 4 + i) * COUT + colb;
#pragma unroll
      for (int t2 = 0; t2 < TC2; t2 += 2) {
        *(float4*)(op + 2 * t2) = make_float4(acc2[i][t2].x, acc2[i][t2].y,
                                              acc2[i][t2 + 1].x, acc2[i][t2 + 1].y);
      }
    }
  }
}

// cls = relu(bn(conf_raw)) @ cls_w + cls_b   (one wave per row; inline BN)
__global__ __launch_bounds__(256) void cls_kernel(const float* __restrict__ craw,
                                                  const float* __restrict__ st,
                                                  const float* __restrict__ clsw,
                                                  const float* __restrict__ clsb,
                                                  float* __restrict__ outc) {
  __shared__ float bnM[256], bnR[256];
  const int tid = threadIdx.x;
  {
    float sum = 0.f, sq = 0.f;
#pragma unroll
    for (int s = 0; s < NSL; ++s) {
      sum += st[tid * NSL + s];
      sq += st[(256 + tid) * NSL + s];
    }
    const float im = 1.0f / 16384.0f;
    const float mu = sum * im;
    const float var = sq * im - mu * mu;
    bnM[tid] = mu;
    bnR[tid] = 1.0f / sqrtf(var + 1e-5f);
  }
  __syncthreads();
  const int wid = tid >> 6, lane = tid & 63;
  const int row = blockIdx.x * 4 + wid;
  const float* cr = craw + (size_t)row * 256;
  float a0 = 0.f, a1 = 0.f, a2 = 0.f;
#pragma unroll 4
  for (int k = lane; k < 256; k += 64) {
    float x = fmaxf((cr[k] - bnM[k]) * bnR[k], 0.f);
    a0 = fmaf(x, clsw[k * 3 + 0], a0);
    a1 = fmaf(x, clsw[k * 3 + 1], a1);
    a2 = fmaf(x, clsw[k * 3 + 2], a2);
  }
#pragma unroll
  for (int off = 32; off; off >>= 1) {
    a0 += __shfl_down(a0, off);
    a1 += __shfl_down(a1, off);
    a2 += __shfl_down(a2, off);
  }
  if (lane == 0) {
    outc[row * 3 + 0] = a0 + clsb[0];
    outc[row * 3 + 1] = a1 + clsb[1];
    outc[row * 3 + 2] = a2 + clsb[2];
  }
}

// ---------------------------------------------------------------------------
extern "C" void kernel_launch(void* const* d_in, const int* in_sizes, int n_in,
                              void* d_out, int out_size, void* d_ws, size_t ws_size,
                              hipStream_t stream) {
  (void)in_sizes; (void)n_in; (void)out_size; (void)ws_size;
  const float* xyz = (const float*)d_in[0];
  const float* feats = (const float*)d_in[1];
  const float* w00 = (const float*)d_in[2];
  const float* w01 = (const float*)d_in[3];
  const float* w02 = (const float*)d_in[4];
  const float* w10 = (const float*)d_in[5];
  const float* w11 = (const float*)d_in[6];
  const float* w12 = (const float*)d_in[7];
  const float* aggw = (const float*)d_in[8];
  const float* aggb = (const float*)d_in[9];
  const float* confw = (const float*)d_in[10];
  const float* clsw = (const float*)d_in[11];
  const float* clsb = (const float*)d_in[12];

  float* outp = (float*)d_out;
  float* nxyz = outp;                               // [BS,3]
  float* hout = outp + (size_t)BS * 3;              // [BS,256]
  float* clsout = hout + (size_t)BS * 256;          // [BS,3]

  char* ws = (char*)d_ws;
  const size_t MB = 1u << 20;
  int* idx0 = (int*)(ws + 0);                       // 1 MB
  int* idx1 = (int*)(ws + 1 * MB);                  // 2 MB
  float* st = (float*)(ws + 3 * MB);                // striped BN stats: 64K floats
  float* pool0 = (float*)(ws + 12 * MB);            // [BS,128]
  float* pool1 = (float*)(ws + 20 * MB);            // [BS,128]
  float* aggraw = (float*)(ws + 28 * MB);           // [BS,256]
  float* confraw = (float*)(ws + 44 * MB);          // [BS,256]
  float* hA = (float*)(ws + 60 * MB);               // [524288,64] (layers 1/2 in-place)

  // striped stats offsets (floats, NSL=32):
  // s0L1=0 s0L2=4096 s0L3=8192 s1L1=16384 s1L2=20480 s1L3=24576
  // agg=32768 conf=49152 ; total 65536 floats
  hipMemsetAsync(st, 0, 65536 * sizeof(float), stream);

  const float iM0 = 1.0f / 262144.0f;   // scale0 rows
  const float iM1 = 1.0f / 524288.0f;   // scale1 rows
  const float iMh = 1.0f / 16384.0f;    // BS rows

  fps_kernel<<<Bb, 1024, 0, stream>>>(xyz, nxyz);
  ballq_kernel<<<BS / 4, 256, 0, stream>>>(xyz, nxyz, idx0, idx1);

  // ---- scale 0 (r=0.4, ns=16) ----
  mlp_gemm<64, 67, 0, 16, false, false><<<4096, 256, 0, stream>>>(
      nullptr, nullptr, nullptr, nullptr, 0.f, 0.f, w00, nullptr,
      idx0, xyz, nxyz, feats, nullptr, hA, st + 0);
  mlp_gemm<64, 64, 1, 1, false, false><<<4096, 256, 0, stream>>>(
      hA, nullptr, st + 0, nullptr, iM0, 0.f, w01, nullptr,
      nullptr, nullptr, nullptr, nullptr, nullptr, hA, st + 4096);
  mlp_gemm<128, 64, 1, 16, true, false><<<4096, 256, 0, stream>>>(
      hA, nullptr, st + 4096, nullptr, iM0, 0.f, w02, nullptr,
      nullptr, nullptr, nullptr, nullptr, nullptr, pool0, st + 8192);

  // ---- scale 1 (r=0.8, ns=32) ----
  mlp_gemm<64, 67, 0, 32, false, false><<<8192, 256, 0, stream>>>(
      nullptr, nullptr, nullptr, nullptr, 0.f, 0.f, w10, nullptr,
      idx1, xyz, nxyz, feats, nullptr, hA, st + 16384);
  mlp_gemm<64, 64, 1, 1, false, false><<<8192, 256, 0, stream>>>(
      hA, nullptr, st + 16384, nullptr, iM1, 0.f, w11, nullptr,
      nullptr, nullptr, nullptr, nullptr, nullptr, hA, st + 20480);
  mlp_gemm<128, 64, 1, 32, true, false><<<8192, 256, 0, stream>>>(
      hA, nullptr, st + 20480, nullptr, iM1, 0.f, w12, nullptr,
      nullptr, nullptr, nullptr, nullptr, nullptr, pool1, st + 24576);

  // ---- aggregation: concat(bn3_0(pool0), bn3_1(pool1)) @ agg_w + agg_b ----
  mlp_gemm<256, 256, 2, 1, false, true><<<256, 256, 0, stream>>>(
      pool0, pool1, st + 8192, st + 24576, iM0, iM1, aggw, aggb,
      nullptr, nullptr, nullptr, nullptr, nullptr, aggraw, st + 32768);

  // ---- confidence hidden layer (MODE 4: bn+relu(aggraw) -> h to d_out,
  //      GEMM against conf_w) ----
  mlp_gemm<256, 256, 4, 1, false, false><<<256, 256, 0, stream>>>(
      aggraw, nullptr, st + 32768, nullptr, iMh, 0.f, confw, nullptr,
      nullptr, nullptr, nullptr, nullptr, hout, confraw, st + 49152);

  // ---- classifier ----
  cls_kernel<<<BS / 4, 256, 0, stream>>>(confraw, st + 49152, clsw, clsb, clsout);
}